// Round 7
// baseline (1054.718 us; speedup 1.0000x reference)
//
#include <hip/hip_runtime.h>

// NeuralCDE: B=256, T=1024, C=8, H=64, W=128.
// Round-6: 1024 threads/block (16 waves, 4 waves/SIMD for real latency
// overlap; round-5 had 2/SIMD and VALU+LDS serialized: 52% VALUBusy).
// Phase A: 8 lanes per h-output (8 MAC each). Phase B: 16-lane groups own
// 8 k-columns (8i x 8k = 64 MAC/lane); W2 fragment = 64 floats/lane so total
// VGPR ~120 fits the 128-reg hard cap at 4 waves/SIMD (no AGPR games).
// Reductions: cndmask+DPP reduce-scatter (xor1/2) + ds_swizzle (xor4/8).
// LDS rows padded to 48B so all b128 reads are bank-disjoint.

#define NB    256
#define TT    1024
#define NSTEP 1023
#define CC    8
#define HH    64
#define WW    128
#define KK    512   // H*C

typedef float v2f __attribute__((ext_vector_type(2)));

__device__ __forceinline__ float fast_tanh(float x) {
    // 1 - 2/(e^{2x}+1); saturates correctly (x->+inf: 1, x->-inf: -1)
    float e = __expf(2.0f * x);
    return 1.0f - 2.0f * __builtin_amdgcn_rcpf(e + 1.0f);
}

__device__ __forceinline__ float dppx1(float x) {   // fetch lane^1 (quad_perm)
    return __builtin_bit_cast(float, __builtin_amdgcn_mov_dpp(
        __builtin_bit_cast(int, x), 0xB1, 0xF, 0xF, true));
}
__device__ __forceinline__ float dppx2(float x) {   // fetch lane^2
    return __builtin_bit_cast(float, __builtin_amdgcn_mov_dpp(
        __builtin_bit_cast(int, x), 0x4E, 0xF, 0xF, true));
}
__device__ __forceinline__ float swz4(float x) {    // fetch lane^4
    return __builtin_bit_cast(float, __builtin_amdgcn_ds_swizzle(
        __builtin_bit_cast(int, x), 0x101F));
}
__device__ __forceinline__ float swz8(float x) {    // fetch lane^8
    return __builtin_bit_cast(float, __builtin_amdgcn_ds_swizzle(
        __builtin_bit_cast(int, x), 0x201F));
}
__device__ __forceinline__ v2f dppx1v(v2f a) { v2f r; r.x = dppx1(a.x); r.y = dppx1(a.y); return r; }
__device__ __forceinline__ v2f dppx2v(v2f a) { v2f r; r.x = dppx2(a.x); r.y = dppx2(a.y); return r; }

__global__ __launch_bounds__(1024)
void cde_kernel(const float* __restrict__ ca, const float* __restrict__ cb,
                const float* __restrict__ cc, const float* __restrict__ cd,
                const float* __restrict__ Wi, const float* __restrict__ bi,
                const float* __restrict__ W1, const float* __restrict__ b1,
                const float* __restrict__ W2, const float* __restrict__ b2,
                float* __restrict__ out)
{
    const int b = blockIdx.x;
    const int t = threadIdx.x;

    // 48B-padded rows: z[8c+q] -> z_pad[c][q]; h[8r+q] -> h_pad[r][q]
    __shared__ __align__(16) float z_pad[8][12];
    __shared__ __align__(16) float h_pad[16][12];
    __shared__ __align__(16) float dx_all[NSTEP * CC];   // 32736 B

    // ---- phase-B mapping: group g of 16 lanes owns k in [8g, 8g+8) ----
    const int g   = t >> 4;      // 0..63
    const int icB = t & 15;      // i-chunk: i in [8*icB, 8*icB+8)
    const bool bit0 = (t & 1), bit1 = (t & 2), bit2 = (t & 4);

    // W2 fragment: w2f[ii][p] = {W2[8*icB+ii][8g+p], W2[8*icB+ii][8g+p+4]}
    v2f w2f[8][4];   // 64 floats
#pragma unroll
    for (int ii = 0; ii < 8; ++ii) {
        const float* wrow = W2 + (size_t)(8 * icB + ii) * KK + 8 * g;
#pragma unroll
        for (int p = 0; p < 4; ++p) {
            v2f w = { wrow[p], wrow[p + 4] };
            w2f[ii][p] = w;
        }
    }
#pragma unroll
    for (int ii = 0; ii < 8; ++ii)
#pragma unroll
        for (int p = 0; p < 4; ++p)
            asm volatile("" : "+v"(w2f[ii][p]));   // block remat into loop
    const float b2r = b2[8 * g + (icB & 7)];       // lane's k = 8g + (icB&7)

    // ---- phase-A mapping: 8 lanes per output j; lane handles 8 i's ----
    const int jA  = t >> 3;      // 0..127
    const int icA = t & 7;       // i in [8*icA, 8*icA+8)
    v2f w1A[4];                  // {W1[8*icA+2q][jA], W1[8*icA+2q+1][jA]}
#pragma unroll
    for (int q = 0; q < 4; ++q) {
        v2f w = { W1[(8 * icA + 2 * q) * WW + jA],
                  W1[(8 * icA + 2 * q + 1) * WW + jA] };
        w1A[q] = w;
    }
#pragma unroll
    for (int q = 0; q < 4; ++q) asm volatile("" : "+v"(w1A[q]));
    const float b1r = b1[jA];

    // ---- preload dx for ALL steps into LDS (coalesced, one-time) ----
    {
        const size_t base = (size_t)b * NSTEP * CC;
        for (int i = t; i < NSTEP * CC; i += 1024)
            dx_all[i] = cb[base + i] + cc[base + i] + 0.75f * cd[base + i];
    }

    // ---- z0 = a0 @ W_init + b_init ----
    if (t < HH) {
        float acc = bi[t];
#pragma unroll
        for (int c = 0; c < CC; ++c)
            acc = fmaf(ca[(size_t)b * NSTEP * CC + c], Wi[c * HH + t], acc);
        z_pad[t >> 3][t & 7] = acc;
        out[(size_t)b * TT * HH + t] = acc;
    }
    __syncthreads();

    float* haddr = &h_pad[jA >> 3][jA & 7];
    float* zaddr = &z_pad[g >> 3][g & 7];
    float* outp  = out + (size_t)b * TT * HH + HH + g;

#pragma unroll 1
    for (int s = 0; s < NSTEP; ++s) {
        // ============ phase A: h = relu(z @ W1 + b1) ============
        // lane reads z[8*icA .. +8): 2 x b128, bank-disjoint (48B rows)
        float4 za = *reinterpret_cast<const float4*>(&z_pad[icA][0]);
        float4 zb = *reinterpret_cast<const float4*>(&z_pad[icA][4]);
        v2f accA = { 0.f, 0.f };
        { v2f zp = { za.x, za.y }; accA = __builtin_elementwise_fma(zp, w1A[0], accA); }
        { v2f zp = { za.z, za.w }; accA = __builtin_elementwise_fma(zp, w1A[1], accA); }
        { v2f zp = { zb.x, zb.y }; accA = __builtin_elementwise_fma(zp, w1A[2], accA); }
        { v2f zp = { zb.z, zb.w }; accA = __builtin_elementwise_fma(zp, w1A[3], accA); }
        float p = accA.x + accA.y;
        p += dppx1(p);
        p += dppx2(p);
        p += swz4(p);                       // sum over 8-lane group
        if (icA == 0) *haddr = fmaxf(p + b1r, 0.0f);
        __syncthreads();

        // ===== phase B: o[k] = h . W2[:,k]; f = tanh(o + b2); z += f@dx =====
        // lane reads h[8*icB .. +8): 2 x b128, bank-disjoint (48B rows)
        float4 ha = *reinterpret_cast<const float4*>(&h_pad[icB][0]);
        float4 hb = *reinterpret_cast<const float4*>(&h_pad[icB][4]);
        v2f A0 = {0,0}, A1 = {0,0}, A2 = {0,0}, A3 = {0,0};
        {
            v2f hs;
            hs.x = ha.x; hs.y = ha.x;
            A0 = __builtin_elementwise_fma(hs, w2f[0][0], A0);
            A1 = __builtin_elementwise_fma(hs, w2f[0][1], A1);
            A2 = __builtin_elementwise_fma(hs, w2f[0][2], A2);
            A3 = __builtin_elementwise_fma(hs, w2f[0][3], A3);
            hs.x = ha.y; hs.y = ha.y;
            A0 = __builtin_elementwise_fma(hs, w2f[1][0], A0);
            A1 = __builtin_elementwise_fma(hs, w2f[1][1], A1);
            A2 = __builtin_elementwise_fma(hs, w2f[1][2], A2);
            A3 = __builtin_elementwise_fma(hs, w2f[1][3], A3);
            hs.x = ha.z; hs.y = ha.z;
            A0 = __builtin_elementwise_fma(hs, w2f[2][0], A0);
            A1 = __builtin_elementwise_fma(hs, w2f[2][1], A1);
            A2 = __builtin_elementwise_fma(hs, w2f[2][2], A2);
            A3 = __builtin_elementwise_fma(hs, w2f[2][3], A3);
            hs.x = ha.w; hs.y = ha.w;
            A0 = __builtin_elementwise_fma(hs, w2f[3][0], A0);
            A1 = __builtin_elementwise_fma(hs, w2f[3][1], A1);
            A2 = __builtin_elementwise_fma(hs, w2f[3][2], A2);
            A3 = __builtin_elementwise_fma(hs, w2f[3][3], A3);
            hs.x = hb.x; hs.y = hb.x;
            A0 = __builtin_elementwise_fma(hs, w2f[4][0], A0);
            A1 = __builtin_elementwise_fma(hs, w2f[4][1], A1);
            A2 = __builtin_elementwise_fma(hs, w2f[4][2], A2);
            A3 = __builtin_elementwise_fma(hs, w2f[4][3], A3);
            hs.x = hb.y; hs.y = hb.y;
            A0 = __builtin_elementwise_fma(hs, w2f[5][0], A0);
            A1 = __builtin_elementwise_fma(hs, w2f[5][1], A1);
            A2 = __builtin_elementwise_fma(hs, w2f[5][2], A2);
            A3 = __builtin_elementwise_fma(hs, w2f[5][3], A3);
            hs.x = hb.z; hs.y = hb.z;
            A0 = __builtin_elementwise_fma(hs, w2f[6][0], A0);
            A1 = __builtin_elementwise_fma(hs, w2f[6][1], A1);
            A2 = __builtin_elementwise_fma(hs, w2f[6][2], A2);
            A3 = __builtin_elementwise_fma(hs, w2f[6][3], A3);
            hs.x = hb.w; hs.y = hb.w;
            A0 = __builtin_elementwise_fma(hs, w2f[7][0], A0);
            A1 = __builtin_elementwise_fma(hs, w2f[7][1], A1);
            A2 = __builtin_elementwise_fma(hs, w2f[7][2], A2);
            A3 = __builtin_elementwise_fma(hs, w2f[7][3], A3);
        }
        // ---- reduce-scatter over the 16-lane group ----
        // A[p] holds o-pair {k=8g+p, k=8g+p+4}; final lane's k = 8g+(icB&7).
        // stage 1 (xor1): retain pairs with p&1 == bit0
        v2f snda = bit0 ? A0 : A1;
        v2f sndb = bit0 ? A2 : A3;
        v2f kpa  = bit0 ? A1 : A0;
        v2f kpb  = bit0 ? A3 : A2;
        v2f B0 = kpa + dppx1v(snda);
        v2f B1 = kpb + dppx1v(sndb);
        // stage 2 (xor2): retain p&2 == bit1
        v2f snd2 = bit1 ? B0 : B1;
        v2f kp2  = bit1 ? B1 : B0;
        v2f Cv = kp2 + dppx2v(snd2);
        // stage 3 (xor4): split the {k, k+4} pair by bit2
        float snd3 = bit2 ? Cv.x : Cv.y;
        float kp3  = bit2 ? Cv.y : Cv.x;
        float o = kp3 + swz4(snd3);
        // stage 4 (xor8): fold the duplicate half-group
        o += swz8(o);

        float f = fast_tanh(o + b2r);

        // z[g] += sum_c f[8g+c]*dx[c]; lane's c = icB&7 (= t&7)
        float val = f * dx_all[s * CC + (t & 7)];
        val += dppx1(val);
        val += dppx2(val);
        val += swz4(val);
        if (icB == 0) {
            float zn = *zaddr + val;
            *zaddr = zn;
            *outp = zn;
        }
        outp += HH;
        __syncthreads();
    }
}

extern "C" void kernel_launch(void* const* d_in, const int* in_sizes, int n_in,
                              void* d_out, int out_size, void* d_ws, size_t ws_size,
                              hipStream_t stream) {
    const float* ca = (const float*)d_in[0];
    const float* cb = (const float*)d_in[1];
    const float* cc = (const float*)d_in[2];
    const float* cd = (const float*)d_in[3];
    const float* Wi = (const float*)d_in[4];
    const float* bi = (const float*)d_in[5];
    const float* W1 = (const float*)d_in[6];
    const float* b1 = (const float*)d_in[7];
    const float* W2 = (const float*)d_in[8];
    const float* b2 = (const float*)d_in[9];
    float* out = (float*)d_out;

    hipLaunchKernelGGL(cde_kernel, dim3(NB), dim3(1024), 0, stream,
                       ca, cb, cc, cd, Wi, bi, W1, b1, W2, b2, out);
}

// Round 8
// 953.351 us; speedup vs baseline: 1.1063x; 1.1063x over previous
//
#include <hip/hip_runtime.h>

// NeuralCDE: B=256, T=1024, C=8, H=64, W=128.
// Round-8: 512 threads (best base = round 5, 827us), two fixes:
//  1. Hand-written v_pk_fma_f32 (default modifiers) for ALL MACs, packed
//     over the i-axis so no operand broadcast is needed. Per-use "v"
//     constraints bias regalloc to keep W2 in real VGPRs (round 5/7 showed
//     AGPR demotion: VGPR_Count 88/56 < fragment size).
//  2. Phase B: 8-lane groups (i-split 8-way) -> h-read 64B/lane (half of
//     round 5), k-set of 8 per group, W2 frag still 128 floats/lane.
//     Reduce-scatter = round-7's verified 3-stage pattern (2 DPP + 1 swz4).
// h_pad[8][20] (80B row stride): the 8 distinct b128 rows cover all 32
// banks -> zero conflict. launch_bounds(512,1) lifts the register budget.

#define NB    256
#define TT    1024
#define NSTEP 1023
#define CC    8
#define HH    64
#define WW    128
#define KK    512   // H*C

typedef float v2f __attribute__((ext_vector_type(2)));

__device__ __forceinline__ void pk_fma(v2f& acc, v2f a, v2f b) {
    asm("v_pk_fma_f32 %0, %1, %2, %0" : "+v"(acc) : "v"(a), "v"(b));
}

__device__ __forceinline__ float fast_tanh(float x) {
    // 1 - 2/(e^{2x}+1); saturates correctly (x->+inf: 1, x->-inf: -1)
    float e = __expf(2.0f * x);
    return 1.0f - 2.0f * __builtin_amdgcn_rcpf(e + 1.0f);
}

__device__ __forceinline__ float dppx1(float x) {   // fetch lane^1 (quad_perm)
    return __builtin_bit_cast(float, __builtin_amdgcn_mov_dpp(
        __builtin_bit_cast(int, x), 0xB1, 0xF, 0xF, true)); // [1,0,3,2]
}
__device__ __forceinline__ float dppx2(float x) {   // fetch lane^2
    return __builtin_bit_cast(float, __builtin_amdgcn_mov_dpp(
        __builtin_bit_cast(int, x), 0x4E, 0xF, 0xF, true)); // [2,3,0,1]
}
__device__ __forceinline__ float swz4(float x) {    // fetch lane^4
    return __builtin_bit_cast(float, __builtin_amdgcn_ds_swizzle(
        __builtin_bit_cast(int, x), 0x101F));
}
__device__ __forceinline__ v2f dppx1v(v2f a) { v2f r; r.x = dppx1(a.x); r.y = dppx1(a.y); return r; }
__device__ __forceinline__ v2f dppx2v(v2f a) { v2f r; r.x = dppx2(a.x); r.y = dppx2(a.y); return r; }

__global__ __launch_bounds__(512, 1)
void cde_kernel(const float* __restrict__ ca, const float* __restrict__ cb,
                const float* __restrict__ cc, const float* __restrict__ cd,
                const float* __restrict__ Wi, const float* __restrict__ bi,
                const float* __restrict__ W1, const float* __restrict__ b1,
                const float* __restrict__ W2, const float* __restrict__ b2,
                float* __restrict__ out)
{
    const int b = blockIdx.x;
    const int t = threadIdx.x;

    __shared__ __align__(16) float z_lds[HH];
    __shared__ __align__(16) float h_pad[8][20];         // 80B rows: bank-disjoint
    __shared__ __align__(16) float dx_all[NSTEP * CC];   // 32736 B

    // ---- phase-B mapping: 8-lane group g8 owns k in [8g8, 8g8+8) ----
    const int g8 = t >> 3;       // 0..63
    const int l  = t & 7;        // i-chunk: i in [16l, 16l+16)
    const bool bit0 = (t & 1), bit1 = (t & 2), bit2 = (t & 4);

    // W2 frag (i-packed): w2p[ii2][p] = {W2[16l+2ii2][8g8+p], W2[16l+2ii2+1][8g8+p]}
    v2f w2p[8][8];   // 128 floats
#pragma unroll
    for (int ii2 = 0; ii2 < 8; ++ii2) {
        const float* r0 = W2 + (size_t)(16 * l + 2 * ii2) * KK + 8 * g8;
        const float* r1 = r0 + KK;
#pragma unroll
        for (int p = 0; p < 8; ++p) {
            v2f w = { r0[p], r1[p] };
            w2p[ii2][p] = w;
        }
    }
#pragma unroll
    for (int ii2 = 0; ii2 < 8; ++ii2)
#pragma unroll
        for (int p = 0; p < 8; ++p)
            asm volatile("" : "+v"(w2p[ii2][p]));   // block remat into loop
    const float b2r = b2[t];     // lane's k = 8*g8 + l == t

    // ---- phase-A mapping: quad per output jA; lane covers 16 i's ----
    const int jA = t >> 2;       // 0..127
    const int gA = t & 3;        // i in [16gA, 16gA+16)
    v2f w1A[8];                  // {W1[16gA+2q][jA], W1[16gA+2q+1][jA]}
#pragma unroll
    for (int q = 0; q < 8; ++q) {
        v2f w = { W1[(16 * gA + 2 * q) * WW + jA],
                  W1[(16 * gA + 2 * q + 1) * WW + jA] };
        w1A[q] = w;
    }
#pragma unroll
    for (int q = 0; q < 8; ++q) asm volatile("" : "+v"(w1A[q]));
    const float b1r = b1[jA];

    // ---- preload dx for ALL steps into LDS (coalesced, one-time) ----
    {
        const size_t base = (size_t)b * NSTEP * CC;
        for (int i = t; i < NSTEP * CC; i += 512)
            dx_all[i] = cb[base + i] + cc[base + i] + 0.75f * cd[base + i];
    }

    // ---- z0 = a0 @ W_init + b_init ----
    if (t < HH) {
        float acc = bi[t];
#pragma unroll
        for (int c = 0; c < CC; ++c)
            acc = fmaf(ca[(size_t)b * NSTEP * CC + c], Wi[c * HH + t], acc);
        z_lds[t] = acc;
        out[(size_t)b * TT * HH + t] = acc;
    }
    __syncthreads();

    const float4* z4 = reinterpret_cast<const float4*>(z_lds);
    float* outp = out + (size_t)b * TT * HH + HH + g8;

#pragma unroll 1
    for (int s = 0; s < NSTEP; ++s) {
        // ============ phase A: h = relu(z @ W1 + b1) ============
        // lane reads z[16gA..+16): 4 b128; 16-way broadcast, 2-way alias (free)
        float4 za = z4[gA * 4 + 0];
        float4 zb = z4[gA * 4 + 1];
        float4 zc = z4[gA * 4 + 2];
        float4 zd = z4[gA * 4 + 3];
        v2f accA = { 0.f, 0.f };
        { v2f zp = { za.x, za.y }; pk_fma(accA, zp, w1A[0]); }
        { v2f zp = { za.z, za.w }; pk_fma(accA, zp, w1A[1]); }
        { v2f zp = { zb.x, zb.y }; pk_fma(accA, zp, w1A[2]); }
        { v2f zp = { zb.z, zb.w }; pk_fma(accA, zp, w1A[3]); }
        { v2f zp = { zc.x, zc.y }; pk_fma(accA, zp, w1A[4]); }
        { v2f zp = { zc.z, zc.w }; pk_fma(accA, zp, w1A[5]); }
        { v2f zp = { zd.x, zd.y }; pk_fma(accA, zp, w1A[6]); }
        { v2f zp = { zd.z, zd.w }; pk_fma(accA, zp, w1A[7]); }
        float p = accA.x + accA.y;
        p += dppx1(p);
        p += dppx2(p);                      // quad butterfly: all 4 lanes have sum
        if (gA == 0) h_pad[jA >> 4][jA & 15] = fmaxf(p + b1r, 0.0f);
        __syncthreads();

        // ===== phase B: o[k] = h . W2[:,k] (8-lane i-split); f=tanh; z += f@dx =====
        // lane reads h[16l..+16): 4 b128, rows cover all 32 banks (no conflict)
        const float4* hp = reinterpret_cast<const float4*>(&h_pad[l][0]);
        float4 h0 = hp[0], h1 = hp[1], h2 = hp[2], h3 = hp[3];
        v2f hpr[8];
        hpr[0].x = h0.x; hpr[0].y = h0.y;  hpr[1].x = h0.z; hpr[1].y = h0.w;
        hpr[2].x = h1.x; hpr[2].y = h1.y;  hpr[3].x = h1.z; hpr[3].y = h1.w;
        hpr[4].x = h2.x; hpr[4].y = h2.y;  hpr[5].x = h2.z; hpr[5].y = h2.w;
        hpr[6].x = h3.x; hpr[6].y = h3.y;  hpr[7].x = h3.z; hpr[7].y = h3.w;
        v2f tmp[8];
#pragma unroll
        for (int p2 = 0; p2 < 8; ++p2) { tmp[p2].x = 0.f; tmp[p2].y = 0.f; }
#pragma unroll
        for (int ii2 = 0; ii2 < 8; ++ii2)
#pragma unroll
            for (int p2 = 0; p2 < 8; ++p2)
                pk_fma(tmp[p2], hpr[ii2], w2p[ii2][p2]);
        // horizontal: Ov[p] = {o(8g8+p), o(8g8+p+4)} partials (this lane's 16 i's)
        v2f Ov0 = { tmp[0].x + tmp[0].y, tmp[4].x + tmp[4].y };
        v2f Ov1 = { tmp[1].x + tmp[1].y, tmp[5].x + tmp[5].y };
        v2f Ov2 = { tmp[2].x + tmp[2].y, tmp[6].x + tmp[6].y };
        v2f Ov3 = { tmp[3].x + tmp[3].y, tmp[7].x + tmp[7].y };
        // ---- reduce-scatter over the 8-lane group (round-7 verified pattern) ----
        // stage 1 (xor1): keep pairs with p&1 == bit0
        v2f snda = bit0 ? Ov0 : Ov1;
        v2f kpa  = bit0 ? Ov1 : Ov0;
        v2f sndb = bit0 ? Ov2 : Ov3;
        v2f kpb  = bit0 ? Ov3 : Ov2;
        v2f B0 = kpa + dppx1v(snda);
        v2f B1 = kpb + dppx1v(sndb);
        // stage 2 (xor2): keep p&2 == bit1
        v2f snd2 = bit1 ? B0 : B1;
        v2f kp2  = bit1 ? B1 : B0;
        v2f Cv = kp2 + dppx2v(snd2);
        // stage 3 (xor4): split the {k, k+4} pair by bit2
        float snd3 = bit2 ? Cv.x : Cv.y;
        float kp3  = bit2 ? Cv.y : Cv.x;
        float o = kp3 + swz4(snd3);

        float f = fast_tanh(o + b2r);

        // z[g8] += sum_c f[8*g8+c] * dx[c]; lane's c = l
        float val = f * dx_all[s * CC + l];
        val += dppx1(val);
        val += dppx2(val);
        val += swz4(val);
        if (l == 0) {
            float zn = z_lds[g8] + val;
            z_lds[g8] = zn;
            *outp = zn;
        }
        outp += HH;
        __syncthreads();
    }
}

extern "C" void kernel_launch(void* const* d_in, const int* in_sizes, int n_in,
                              void* d_out, int out_size, void* d_ws, size_t ws_size,
                              hipStream_t stream) {
    const float* ca = (const float*)d_in[0];
    const float* cb = (const float*)d_in[1];
    const float* cc = (const float*)d_in[2];
    const float* cd = (const float*)d_in[3];
    const float* Wi = (const float*)d_in[4];
    const float* bi = (const float*)d_in[5];
    const float* W1 = (const float*)d_in[6];
    const float* b1 = (const float*)d_in[7];
    const float* W2 = (const float*)d_in[8];
    const float* b2 = (const float*)d_in[9];
    float* out = (float*)d_out;

    hipLaunchKernelGGL(cde_kernel, dim3(NB), dim3(512), 0, stream,
                       ca, cb, cc, cd, Wi, bi, W1, b1, W2, b2, out);
}